// Round 15
// baseline (253.664 us; speedup 1.0000x reference)
//
#include <hip/hip_runtime.h>

typedef _Float16 f16;
typedef f16   f16x8 __attribute__((ext_vector_type(8)));
typedef float f32x4 __attribute__((ext_vector_type(4)));
typedef __attribute__((address_space(3))) char as3char;

#define MFMA16(a, b, c) __builtin_amdgcn_mfma_f32_16x16x32_f16((a), (b), (c), 0, 0, 0)

// ---- weight images in d_ws (f16 units). granule = [64n][64k^swz] = 4096 f16 = 8KB ----
// All granules except w1 have k-rows pre-permuted by sigma (matches in-register
// B-frag packing of the previous layer's D output). w1 keeps natural k (x loaded raw).
#define IMG_W1   0        // 8 granules: (kq*2+nh), natural k
#define IMG_W2   32768    // {w2 kh0, w2 kh1}, sigma k within each 64-half
#define IMG_GW1  40960    // [32n][64k sigma]
#define IMG_E    43008    // per e (16384): h*8192 + {ew1 colhalf h @0, ew2 rowhalf h @4096}, sigma
#define IMG_SWH  108544   // sw(4096) | hw1[0](2048) | hw1[1](2048) | hw1[2](2048), sigma

__device__ __forceinline__ float silu_f(float v) {
    return v * __builtin_amdgcn_rcpf(1.0f + __expf(-v));
}

// sigma: D-frag register order -> k feature. s = 32ks + 8q + i.
__device__ __forceinline__ int sigma_k(int s) {
    const int ks = s >> 5, qq = (s >> 3) & 3, i = s & 7;
    return 16 * (2 * ks + (i >> 2)) + 4 * qq + (i & 3);
}

// ============ prep: fp32 src[K][N] block -> f16 granule [n][slot ^ ((n&7)<<3)] ============
template<bool SIG>
__device__ void conv_blk(const float* __restrict__ src, f16* __restrict__ dst,
                         int srcN, int k0, int n0, int KB, int NB, int tid, int nth) {
    for (int idx = tid; idx < KB * NB; idx += nth) {
        const int s = idx / NB, nn = idx - s * NB;      // s = logical k-slot
        const int k = SIG ? sigma_k(s) : s;
        dst[nn * KB + (s ^ ((nn & 7) << 3))] = (f16)src[(long)(k0 + k) * srcN + n0 + nn];
    }
}

__global__ void prep_weights(const float* __restrict__ w1, const float* __restrict__ w2,
                             const float* __restrict__ gw1, const float* __restrict__ ew1,
                             const float* __restrict__ ew2, const float* __restrict__ sw,
                             const float* __restrict__ hw1, f16* __restrict__ ws) {
    const int tid = blockIdx.x * 256 + threadIdx.x;
    const int nth = gridDim.x * 256;
    for (int kq = 0; kq < 4; ++kq)
        for (int nh = 0; nh < 2; ++nh)
            conv_blk<false>(w1, ws + IMG_W1 + (kq * 2 + nh) * 4096, 128, kq * 64, nh * 64, 64, 64, tid, nth);
    for (int kh = 0; kh < 2; ++kh)
        conv_blk<true>(w2, ws + IMG_W2 + kh * 4096, 64, kh * 64, 0, 64, 64, tid, nth);
    conv_blk<true>(gw1, ws + IMG_GW1, 32, 0, 0, 64, 32, tid, nth);
    for (int e = 0; e < 4; ++e)
        for (int h = 0; h < 2; ++h) {
            conv_blk<true>(ew1 + e * 8192, ws + IMG_E + e * 16384 + h * 8192,        128, 0, h * 64, 64, 64, tid, nth);
            conv_blk<true>(ew2 + e * 8192, ws + IMG_E + e * 16384 + h * 8192 + 4096,  64, h * 64, 0, 64, 64, tid, nth);
        }
    conv_blk<true>(sw, ws + IMG_SWH, 64, 0, 0, 64, 64, tid, nth);
    for (int h = 0; h < 3; ++h)
        conv_blk<true>(hw1 + h * 2048, ws + IMG_SWH + 4096 + h * 2048, 32, 0, 0, 64, 32, tid, nth);
}

// ============ async global->LDS staging: 1KB chunks round-robined over 4 waves ============
template<int BYTES>
__device__ __forceinline__ void stage4(const f16* __restrict__ g, as3char* l, int wv, int lane) {
    constexpr int CH = BYTES / 1024;
    #pragma unroll
    for (int ch = 0; ch < CH; ++ch)
        if ((ch & 3) == wv)
            __builtin_amdgcn_global_load_lds(
                (const __attribute__((address_space(1))) void*)((const char*)g + ch * 1024 + lane * 16),
                (__attribute__((address_space(3))) void*)(l + ch * 1024), 16, 0, 0);
}

// ============ weight A-frag from swizzled LDS granule ============
__device__ __forceinline__ int swzW(int n) { return (n & 7) << 3; }

__device__ __forceinline__ f16x8 ldW(const f16* base, int row_base, int k0, int lane) {
    const int r = row_base + (lane & 15);
    const int k = k0 + ((lane >> 4) << 3);
    return *(const f16x8*)(base + r * 64 + (k ^ swzW(r)));
}

// NT n-tiles: acc[n] += W(A) x act(B)
template<int NT>
__device__ __forceinline__ void mmN(const f16x8 bf[2], const f16* wb, f32x4* acc, int lane) {
    #pragma unroll
    for (int ks = 0; ks < 2; ++ks)
        #pragma unroll
        for (int n = 0; n < NT; ++n) {
            const f16x8 w = ldW(wb, n * 16, ks * 32, lane);
            acc[n] = MFMA16(w, bf[ks], acc[n]);
        }
}

// D-acc (4 tiles) -> B-frags, register-only (order matches sigma)
__device__ __forceinline__ void silu_pack(const f32x4* a4, f16x8 bf[2]) {
    #pragma unroll
    for (int ks = 0; ks < 2; ++ks)
        #pragma unroll
        for (int i = 0; i < 8; ++i)
            bf[ks][i] = (f16)silu_f(a4[2 * ks + (i >> 2)][i & 3]);
}
__device__ __forceinline__ void pack_raw(const f32x4* a4, f16x8 bf[2]) {
    #pragma unroll
    for (int ks = 0; ks < 2; ++ks)
        #pragma unroll
        for (int i = 0; i < 8; ++i)
            bf[ks][i] = (f16)a4[2 * ks + (i >> 2)][i & 3];
}

__device__ __forceinline__ f16x8 cvt8(float4 a, float4 b) {
    f16x8 r;
    r[0] = (f16)a.x; r[1] = (f16)a.y; r[2] = (f16)a.z; r[3] = (f16)a.w;
    r[4] = (f16)b.x; r[5] = (f16)b.y; r[6] = (f16)b.z; r[7] = (f16)b.w;
    return r;
}

// sum across the 4 quad lanes {j, j+16, j+32, j+48}
__device__ __forceinline__ float qreduce(float v) {
    v += __shfl_xor(v, 16, 64);
    v += __shfl_xor(v, 32, 64);
    return v;
}

__global__ __launch_bounds__(256, 8)
void fused_net_mfma(const float* __restrict__ x,   const f16* __restrict__ wsp,
                    const float* __restrict__ b1,  const float* __restrict__ lng,
                    const float* __restrict__ lnb, const float* __restrict__ b2,
                    const float* __restrict__ eb1, const float* __restrict__ eb2,
                    const float* __restrict__ gb1, const float* __restrict__ gw2,
                    const float* __restrict__ gb2, const float* __restrict__ sb,
                    const float* __restrict__ hb1, const float* __restrict__ hw2,
                    const float* __restrict__ hb2, float* __restrict__ out)
{
    // 20 KB LDS: WA 8K | WB 8K | G 4K. 8 blocks/CU = 160 KB (full pool), 32 waves/CU.
    // grid 2048 = 256 CU x 8 -> exactly one round, no ragged tail.
    __shared__ __align__(16) f16 lds[10240];
    as3char* const LB = (as3char*)lds;
    const int lane = threadIdx.x & 63;
    const int wv   = threadIdx.x >> 6;
    const int j    = lane & 15;           // batch row within wave tile
    const int q    = lane >> 4;           // quad index (feature group)
    const int q4   = q * 4;
    f16* const WA = lds;          as3char* const WA_3 = LB;
    f16* const WB = lds + 4096;   as3char* const WB_3 = LB + 8192;
    f16* const G  = lds + 8192;   as3char* const G_3  = LB + 16384;

    const long row0 = (long)blockIdx.x * 64 + wv * 16;
    const float* xrow = x + (row0 + j) * 256 + q * 8;

    // ---- prologue: w1 g0 -> WA, gw1 -> G; x quarter 0 -> regs ----
    stage4<8192>(wsp + IMG_W1, WA_3, wv, lane);
    stage4<4096>(wsp + IMG_GW1, G_3, wv, lane);
    float4 xr[4];
    xr[0] = *(const float4*)(xrow);      xr[1] = *(const float4*)(xrow + 4);
    xr[2] = *(const float4*)(xrow + 32); xr[3] = *(const float4*)(xrow + 36);
    __syncthreads();

    // ================= stem1: 8 pipelined granule phases =================
    f32x4 acc[8];
    #pragma unroll
    for (int t = 0; t < 8; ++t)
        #pragma unroll
        for (int g = 0; g < 4; ++g) acc[t][g] = b1[t * 16 + q4 + g];

    #pragma unroll 1
    for (int kq = 0; kq < 4; ++kq) {
        const f16* curA = (kq & 1) ? WB : WA;
        as3char* othA   = (kq & 1) ? WA_3 : WB_3;
        const f16* curB = (kq & 1) ? WA : WB;
        as3char* othB   = (kq & 1) ? WB_3 : WA_3;

        // phase 2kq (cur: w1(kq,nh0)): stage w1(kq,nh1)
        stage4<8192>(wsp + IMG_W1 + (kq * 2 + 1) * 4096, othA, wv, lane);
        f16x8 af[2];
        af[0] = cvt8(xr[0], xr[1]);
        af[1] = cvt8(xr[2], xr[3]);
        mmN<4>(af, curA, acc, lane);
        __syncthreads();

        // phase 2kq+1 (cur: w1(kq,nh1)): stage next
        if (kq < 3) stage4<8192>(wsp + IMG_W1 + (kq + 1) * 2 * 4096, othB, wv, lane);
        else        stage4<8192>(wsp + IMG_W2, othB, wv, lane);
        if (kq < 3) {
            const float* xb = xrow + (kq + 1) * 64;
            xr[0] = *(const float4*)(xb);      xr[1] = *(const float4*)(xb + 4);
            xr[2] = *(const float4*)(xb + 32); xr[3] = *(const float4*)(xb + 36);
        }
        mmN<4>(af, curB, acc + 4, lane);
        __syncthreads();
    }

    // ---- LN stats: per-lane partial + 2-shfl quad reduce ----
    float s = 0.f, ss = 0.f;
    #pragma unroll
    for (int t = 0; t < 8; ++t)
        #pragma unroll
        for (int g = 0; g < 4; ++g) { const float v = acc[t][g]; s += v; ss += v * v; }
    s = qreduce(s); ss = qreduce(ss);
    const float mu  = s * 0.0078125f;
    const float rsv = rsqrtf(ss * 0.0078125f - mu * mu + 1e-5f);

    // ================= phase 8 (WA: w2 kh0): stage w2kh1 -> WB =================
    f32x4 a2[4];
    #pragma unroll
    for (int t = 0; t < 4; ++t)
        #pragma unroll
        for (int g = 0; g < 4; ++g) a2[t][g] = b2[t * 16 + q4 + g];
    stage4<8192>(wsp + IMG_W2 + 4096, WB_3, wv, lane);
    {
        f16x8 bf[2];
        #pragma unroll
        for (int ks = 0; ks < 2; ++ks)
            #pragma unroll
            for (int i = 0; i < 8; ++i) {
                const int t = 2 * ks + (i >> 2), g = i & 3, f = 16 * t + q4 + g;
                bf[ks][i] = (f16)silu_f((acc[t][g] - mu) * rsv * lng[f] + lnb[f]);
            }
        mmN<4>(bf, WA, a2, lane);
    }
    __syncthreads();

    // ================= phase 9 (WB: w2 kh1): stage e0 ew1h0 -> WA; gate ===========
    stage4<8192>(wsp + IMG_E, WA_3, wv, lane);
    f16x8 hbB[2];
    f32x4 gwt;
    {
        f16x8 bf[2];
        #pragma unroll
        for (int ks = 0; ks < 2; ++ks)
            #pragma unroll
            for (int i = 0; i < 8; ++i) {
                const int t = 4 + 2 * ks + (i >> 2), g = i & 3, f = 16 * t + q4 + g;
                bf[ks][i] = (f16)silu_f((acc[t][g] - mu) * rsv * lng[f] + lnb[f]);
            }
        mmN<4>(bf, WB, a2, lane);
        silu_pack(a2, hbB);

        // gate: N=32 (2 tiles), all in-register
        f32x4 ag[2];
        #pragma unroll
        for (int t = 0; t < 2; ++t)
            #pragma unroll
            for (int g = 0; g < 4; ++g) ag[t][g] = gb1[t * 16 + q4 + g];
        mmN<2>(hbB, G, ag, lane);
        f32x4 pg = {0, 0, 0, 0};
        #pragma unroll
        for (int t = 0; t < 2; ++t)
            #pragma unroll
            for (int g = 0; g < 4; ++g) {
                const int f = 16 * t + q4 + g;
                const f32x4 w4 = *(const f32x4*)(gw2 + f * 4);
                pg += silu_f(ag[t][g]) * w4;
            }
        #pragma unroll
        for (int o = 0; o < 4; ++o) pg[o] = qreduce(pg[o]);
        const f32x4 l = pg + *(const f32x4*)gb2;
        const float mx = fmaxf(fmaxf(l[0], l[1]), fmaxf(l[2], l[3]));
        f32x4 ee;
        #pragma unroll
        for (int o = 0; o < 4; ++o) ee[o] = __expf(l[o] - mx);
        gwt = ee * __builtin_amdgcn_rcpf(ee[0] + ee[1] + ee[2] + ee[3]);
    }
    __syncthreads();   // e0 ew1h0 ready in WA

    // ================= 4 experts: 4 pipelined phases each =================
    f32x4 moe[4] = {{0,0,0,0},{0,0,0,0},{0,0,0,0},{0,0,0,0}};
    #pragma unroll 1
    for (int e = 0; e < 4; ++e) {
        const f16* ebase = wsp + IMG_E + e * 16384;
        f32x4 a2e[4];
        #pragma unroll
        for (int t = 0; t < 4; ++t)
            #pragma unroll
            for (int g = 0; g < 4; ++g) a2e[t][g] = eb2[e * 64 + t * 16 + q4 + g];
        f16x8 eaB[2];
        // --- A (WA: ew1 h0): stage ew2h0 -> WB ---
        stage4<8192>(ebase + 4096 * 2, WB_3, wv, lane);   // note: +8192 B = +4096 f16
        {
            f32x4 aa[4];
            #pragma unroll
            for (int t = 0; t < 4; ++t)
                #pragma unroll
                for (int g = 0; g < 4; ++g) aa[t][g] = eb1[e * 128 + t * 16 + q4 + g];
            mmN<4>(hbB, WA, aa, lane);
            silu_pack(aa, eaB);
        }
        __syncthreads();
        // --- B (WB: ew2 h0): stage ew1h1 -> WA ---
        stage4<8192>(ebase + 8192, WA_3, wv, lane);
        mmN<4>(eaB, WB, a2e, lane);
        __syncthreads();
        // --- C (WA: ew1 h1): stage ew2h1 -> WB ---
        stage4<8192>(ebase + 8192 + 4096, WB_3, wv, lane);
        {
            f32x4 aa[4];
            #pragma unroll
            for (int t = 0; t < 4; ++t)
                #pragma unroll
                for (int g = 0; g < 4; ++g) aa[t][g] = eb1[e * 128 + 64 + t * 16 + q4 + g];
            mmN<4>(hbB, WA, aa, lane);
            silu_pack(aa, eaB);
        }
        __syncthreads();
        // --- D (WB: ew2 h1): stage next ew1h0 (or sw) -> WA ---
        if (e < 3) stage4<8192>(wsp + IMG_E + (e + 1) * 16384, WA_3, wv, lane);
        else       stage4<8192>(wsp + IMG_SWH, WA_3, wv, lane);
        mmN<4>(eaB, WB, a2e, lane);
        const float ge = (e == 0) ? gwt[0] : (e == 1) ? gwt[1] : (e == 2) ? gwt[2] : gwt[3];
        #pragma unroll
        for (int t = 0; t < 4; ++t)
            #pragma unroll
            for (int g = 0; g < 4; ++g)
                moe[t][g] += silu_f(a2e[t][g]) * ge;
        __syncthreads();
    }

    // ================= feat (WA: sw): stage hw1[0,1] -> WB, hw1[2] -> G ============
    stage4<8192>(wsp + IMG_SWH + 4096, WB_3, wv, lane);
    stage4<4096>(wsp + IMG_SWH + 8192, G_3, wv, lane);
    f16x8 featB[2];
    {
        f16x8 moeB[2];
        pack_raw(moe, moeB);
        f32x4 fs[4];
        #pragma unroll
        for (int t = 0; t < 4; ++t)
            #pragma unroll
            for (int g = 0; g < 4; ++g) fs[t][g] = sb[t * 16 + q4 + g];
        mmN<4>(moeB, WA, fs, lane);
        silu_pack(fs, featB);
    }
    __syncthreads();   // hw1[0,1] in WB, hw1[2] in G

    // ================= heads (WB: hw1[0]@0, hw1[1]@2048; G: hw1[2]) ================
    #pragma unroll
    for (int h = 0; h < 3; ++h) {
        const f16* hw = (h == 0) ? WB : (h == 1) ? (WB + 2048) : G;
        f32x4 ah[2];
        #pragma unroll
        for (int t = 0; t < 2; ++t)
            #pragma unroll
            for (int g = 0; g < 4; ++g) ah[t][g] = hb1[h * 32 + t * 16 + q4 + g];
        mmN<2>(featB, hw, ah, lane);
        float ph = 0.f;
        #pragma unroll
        for (int t = 0; t < 2; ++t)
            #pragma unroll
            for (int g = 0; g < 4; ++g)
                ph += silu_f(ah[t][g]) * hw2[h * 32 + t * 16 + q4 + g];
        ph = qreduce(ph);
        if (q == h) out[(row0 + j) * 3 + h] = ph + hb2[h];
    }
}

extern "C" void kernel_launch(void* const* d_in, const int* in_sizes, int n_in,
                              void* d_out, int out_size, void* d_ws, size_t ws_size,
                              hipStream_t stream) {
    const float* x    = (const float*)d_in[0];
    const float* w1   = (const float*)d_in[1];
    const float* b1   = (const float*)d_in[2];
    const float* lng  = (const float*)d_in[3];
    const float* lnb  = (const float*)d_in[4];
    const float* w2   = (const float*)d_in[5];
    const float* b2   = (const float*)d_in[6];
    const float* ew1  = (const float*)d_in[7];
    const float* eb1  = (const float*)d_in[8];
    const float* ew2  = (const float*)d_in[9];
    const float* eb2  = (const float*)d_in[10];
    const float* gw1  = (const float*)d_in[11];
    const float* gb1  = (const float*)d_in[12];
    const float* gw2  = (const float*)d_in[13];
    const float* gb2  = (const float*)d_in[14];
    const float* sw   = (const float*)d_in[15];
    const float* sb   = (const float*)d_in[16];
    const float* hw1  = (const float*)d_in[17];
    const float* hb1  = (const float*)d_in[18];
    const float* hw2  = (const float*)d_in[19];
    const float* hb2  = (const float*)d_in[20];
    float* out = (float*)d_out;
    f16* ws = (f16*)d_ws;

    hipLaunchKernelGGL(prep_weights, dim3(64), dim3(256), 0, stream,
                       w1, w2, gw1, ew1, ew2, sw, hw1, ws);

    const int B = in_sizes[0] / 256;
    const int grid = B / 64;
    hipLaunchKernelGGL(fused_net_mfma, dim3(grid), dim3(256), 0, stream,
                       x, ws, b1, lng, lnb, b2, eb1, eb2, gb1, gw2, gb2,
                       sb, hb1, hw2, hb2, out);
}

// Round 16
// 129.891 us; speedup vs baseline: 1.9529x; 1.9529x over previous
//
#include <hip/hip_runtime.h>

typedef _Float16 f16;
typedef f16   f16x8 __attribute__((ext_vector_type(8)));
typedef float f32x4 __attribute__((ext_vector_type(4)));
typedef __attribute__((address_space(3))) char as3char;

#define MFMA16(a, b, c) __builtin_amdgcn_mfma_f32_16x16x32_f16((a), (b), (c), 0, 0, 0)

// ---- weight images in d_ws (f16 units). granule = [64n][64k^swz] = 4096 f16 = 8KB ----
#define IMG_W1   0        // 8 granules: (kq*2+nh), natural k
#define IMG_W2   32768    // {w2 kh0, w2 kh1}, sigma k within each 64-half
#define IMG_GW1  40960    // [32n][64k sigma]
#define IMG_E    43008    // per e (16384): h*8192 + {ew1 colhalf h @0, ew2 rowhalf h @4096}, sigma
#define IMG_SWH  108544   // sw(4096) | hw1[0](2048) | hw1[1](2048) | hw1[2](2048), sigma

__device__ __forceinline__ float silu_f(float v) {
    return v * __builtin_amdgcn_rcpf(1.0f + __expf(-v));
}

// sigma: D-frag register order -> k feature. s = 32ks + 8q + i.
__device__ __forceinline__ int sigma_k(int s) {
    const int ks = s >> 5, qq = (s >> 3) & 3, i = s & 7;
    return 16 * (2 * ks + (i >> 2)) + 4 * qq + (i & 3);
}

// ============ prep: fp32 src[K][N] block -> f16 granule [n][slot ^ ((n&7)<<3)] ============
template<bool SIG>
__device__ void conv_blk(const float* __restrict__ src, f16* __restrict__ dst,
                         int srcN, int k0, int n0, int KB, int NB, int tid, int nth) {
    for (int idx = tid; idx < KB * NB; idx += nth) {
        const int s = idx / NB, nn = idx - s * NB;      // s = logical k-slot
        const int k = SIG ? sigma_k(s) : s;
        dst[nn * KB + (s ^ ((nn & 7) << 3))] = (f16)src[(long)(k0 + k) * srcN + n0 + nn];
    }
}

__global__ void prep_weights(const float* __restrict__ w1, const float* __restrict__ w2,
                             const float* __restrict__ gw1, const float* __restrict__ ew1,
                             const float* __restrict__ ew2, const float* __restrict__ sw,
                             const float* __restrict__ hw1, f16* __restrict__ ws) {
    const int tid = blockIdx.x * 256 + threadIdx.x;
    const int nth = gridDim.x * 256;
    for (int kq = 0; kq < 4; ++kq)
        for (int nh = 0; nh < 2; ++nh)
            conv_blk<false>(w1, ws + IMG_W1 + (kq * 2 + nh) * 4096, 128, kq * 64, nh * 64, 64, 64, tid, nth);
    for (int kh = 0; kh < 2; ++kh)
        conv_blk<true>(w2, ws + IMG_W2 + kh * 4096, 64, kh * 64, 0, 64, 64, tid, nth);
    conv_blk<true>(gw1, ws + IMG_GW1, 32, 0, 0, 64, 32, tid, nth);
    for (int e = 0; e < 4; ++e)
        for (int h = 0; h < 2; ++h) {
            conv_blk<true>(ew1 + e * 8192, ws + IMG_E + e * 16384 + h * 8192,        128, 0, h * 64, 64, 64, tid, nth);
            conv_blk<true>(ew2 + e * 8192, ws + IMG_E + e * 16384 + h * 8192 + 4096,  64, h * 64, 0, 64, 64, tid, nth);
        }
    conv_blk<true>(sw, ws + IMG_SWH, 64, 0, 0, 64, 64, tid, nth);
    for (int h = 0; h < 3; ++h)
        conv_blk<true>(hw1 + h * 2048, ws + IMG_SWH + 4096 + h * 2048, 32, 0, 0, 64, 32, tid, nth);
}

// ============ async global->LDS staging: 1KB chunks round-robined over 4 waves ============
template<int BYTES>
__device__ __forceinline__ void stage4(const f16* __restrict__ g, as3char* l, int wv, int lane) {
    constexpr int CH = BYTES / 1024;
    #pragma unroll
    for (int ch = 0; ch < CH; ++ch)
        if ((ch & 3) == wv)
            __builtin_amdgcn_global_load_lds(
                (const __attribute__((address_space(1))) void*)((const char*)g + ch * 1024 + lane * 16),
                (__attribute__((address_space(3))) void*)(l + ch * 1024), 16, 0, 0);
}

// ============ weight A-frag from swizzled LDS granule ============
__device__ __forceinline__ int swzW(int n) { return (n & 7) << 3; }

__device__ __forceinline__ f16x8 ldW(const f16* base, int row_base, int k0, int lane) {
    const int r = row_base + (lane & 15);
    const int k = k0 + ((lane >> 4) << 3);
    return *(const f16x8*)(base + r * 64 + (k ^ swzW(r)));
}

// NT n-tiles: acc[n] += W(A) x act(B)
template<int NT>
__device__ __forceinline__ void mmN(const f16x8 bf[2], const f16* wb, f32x4* acc, int lane) {
    #pragma unroll
    for (int ks = 0; ks < 2; ++ks)
        #pragma unroll
        for (int n = 0; n < NT; ++n) {
            const f16x8 w = ldW(wb, n * 16, ks * 32, lane);
            acc[n] = MFMA16(w, bf[ks], acc[n]);
        }
}

// D-acc (4 tiles) -> B-frags, register-only (order matches sigma)
__device__ __forceinline__ void silu_pack(const f32x4* a4, f16x8 bf[2]) {
    #pragma unroll
    for (int ks = 0; ks < 2; ++ks)
        #pragma unroll
        for (int i = 0; i < 8; ++i)
            bf[ks][i] = (f16)silu_f(a4[2 * ks + (i >> 2)][i & 3]);
}
__device__ __forceinline__ void pack_raw(const f32x4* a4, f16x8 bf[2]) {
    #pragma unroll
    for (int ks = 0; ks < 2; ++ks)
        #pragma unroll
        for (int i = 0; i < 8; ++i)
            bf[ks][i] = (f16)a4[2 * ks + (i >> 2)][i & 3];
}

__device__ __forceinline__ f16x8 cvt8(float4 a, float4 b) {
    f16x8 r;
    r[0] = (f16)a.x; r[1] = (f16)a.y; r[2] = (f16)a.z; r[3] = (f16)a.w;
    r[4] = (f16)b.x; r[5] = (f16)b.y; r[6] = (f16)b.z; r[7] = (f16)b.w;
    return r;
}

// sum across the 4 quad lanes {j, j+16, j+32, j+48}
__device__ __forceinline__ float qreduce(float v) {
    v += __shfl_xor(v, 16, 64);
    v += __shfl_xor(v, 32, 64);
    return v;
}

__global__ __launch_bounds__(256, 6)
void fused_net_mfma(const float* __restrict__ x,   const f16* __restrict__ wsp,
                    const float* __restrict__ b1,  const float* __restrict__ lng,
                    const float* __restrict__ lnb, const float* __restrict__ b2,
                    const float* __restrict__ eb1, const float* __restrict__ eb2,
                    const float* __restrict__ gb1, const float* __restrict__ gw2,
                    const float* __restrict__ gb2, const float* __restrict__ sb,
                    const float* __restrict__ hb1, const float* __restrict__ hw2,
                    const float* __restrict__ hb2, float* __restrict__ out)
{
    // 20 KB LDS: WA 8K | WB 8K | G 4K. 6 blocks/CU = 120 KB, 24 waves/CU.
    __shared__ __align__(16) f16 lds[10240];
    as3char* const LB = (as3char*)lds;
    const int lane = threadIdx.x & 63;
    const int wv   = threadIdx.x >> 6;
    const int j    = lane & 15;           // batch row within wave tile
    const int q    = lane >> 4;           // quad index (feature group)
    const int q4   = q * 4;
    f16* const WA = lds;          as3char* const WA_3 = LB;
    f16* const WB = lds + 4096;   as3char* const WB_3 = LB + 8192;
    f16* const G  = lds + 8192;   as3char* const G_3  = LB + 16384;

    const long row0 = (long)blockIdx.x * 64 + wv * 16;
    const float* xrow = x + (row0 + j) * 256 + q * 8;

    // ---- prologue: w1 g0 -> WA, gw1 -> G; x quarter 0 -> regs ----
    stage4<8192>(wsp + IMG_W1, WA_3, wv, lane);
    stage4<4096>(wsp + IMG_GW1, G_3, wv, lane);
    float4 xr[4];
    xr[0] = *(const float4*)(xrow);      xr[1] = *(const float4*)(xrow + 4);
    xr[2] = *(const float4*)(xrow + 32); xr[3] = *(const float4*)(xrow + 36);
    __syncthreads();

    // ================= stem1: 8 pipelined granule phases =================
    f32x4 acc[8];
    #pragma unroll
    for (int t = 0; t < 8; ++t)
        acc[t] = *(const f32x4*)(b1 + t * 16 + q4);

    #pragma unroll 1
    for (int kq = 0; kq < 4; ++kq) {
        const f16* curA = (kq & 1) ? WB : WA;
        as3char* othA   = (kq & 1) ? WA_3 : WB_3;
        const f16* curB = (kq & 1) ? WA : WB;
        as3char* othB   = (kq & 1) ? WB_3 : WA_3;

        // phase 2kq (cur: w1(kq,nh0)): stage w1(kq,nh1)
        stage4<8192>(wsp + IMG_W1 + (kq * 2 + 1) * 4096, othA, wv, lane);
        f16x8 af[2];
        af[0] = cvt8(xr[0], xr[1]);
        af[1] = cvt8(xr[2], xr[3]);
        mmN<4>(af, curA, acc, lane);
        __syncthreads();

        // phase 2kq+1 (cur: w1(kq,nh1)): stage next
        if (kq < 3) stage4<8192>(wsp + IMG_W1 + (kq + 1) * 2 * 4096, othB, wv, lane);
        else        stage4<8192>(wsp + IMG_W2, othB, wv, lane);
        if (kq < 3) {
            const float* xb = xrow + (kq + 1) * 64;
            xr[0] = *(const float4*)(xb);      xr[1] = *(const float4*)(xb + 4);
            xr[2] = *(const float4*)(xb + 32); xr[3] = *(const float4*)(xb + 36);
        }
        mmN<4>(af, curB, acc + 4, lane);
        __syncthreads();
    }

    // ---- LN stats: per-lane partial + 2-shfl quad reduce ----
    float s = 0.f, ss = 0.f;
    #pragma unroll
    for (int t = 0; t < 8; ++t)
        #pragma unroll
        for (int g = 0; g < 4; ++g) { const float v = acc[t][g]; s += v; ss += v * v; }
    s = qreduce(s); ss = qreduce(ss);
    const float mu  = s * 0.0078125f;
    const float rsv = rsqrtf(ss * 0.0078125f - mu * mu + 1e-5f);

    // ================= phase 8 (WA: w2 kh0): stage w2kh1 -> WB =================
    f32x4 a2[4];
    #pragma unroll
    for (int t = 0; t < 4; ++t)
        a2[t] = *(const f32x4*)(b2 + t * 16 + q4);
    stage4<8192>(wsp + IMG_W2 + 4096, WB_3, wv, lane);
    {
        f16x8 bf[2];
        #pragma unroll
        for (int ks = 0; ks < 2; ++ks)
            #pragma unroll
            for (int u = 0; u < 2; ++u) {
                const int t = 2 * ks + u;
                const f32x4 g4 = *(const f32x4*)(lng + 16 * t + q4);
                const f32x4 bb4 = *(const f32x4*)(lnb + 16 * t + q4);
                #pragma unroll
                for (int g = 0; g < 4; ++g)
                    bf[ks][4 * u + g] = (f16)silu_f((acc[t][g] - mu) * rsv * g4[g] + bb4[g]);
            }
        mmN<4>(bf, WA, a2, lane);
    }
    __syncthreads();

    // ================= phase 9 (WB: w2 kh1): stage e0 ew1h0 -> WA; gate ===========
    stage4<8192>(wsp + IMG_E, WA_3, wv, lane);
    f16x8 hbB[2];
    f32x4 gwt;
    {
        f16x8 bf[2];
        #pragma unroll
        for (int ks = 0; ks < 2; ++ks)
            #pragma unroll
            for (int u = 0; u < 2; ++u) {
                const int t = 4 + 2 * ks + u;
                const f32x4 g4 = *(const f32x4*)(lng + 16 * t + q4);
                const f32x4 bb4 = *(const f32x4*)(lnb + 16 * t + q4);
                #pragma unroll
                for (int g = 0; g < 4; ++g)
                    bf[ks][4 * u + g] = (f16)silu_f((acc[t][g] - mu) * rsv * g4[g] + bb4[g]);
            }
        mmN<4>(bf, WB, a2, lane);
        silu_pack(a2, hbB);

        // gate: N=32 (2 tiles), all in-register
        f32x4 ag[2];
        #pragma unroll
        for (int t = 0; t < 2; ++t)
            ag[t] = *(const f32x4*)(gb1 + t * 16 + q4);
        mmN<2>(hbB, G, ag, lane);
        f32x4 pg = {0, 0, 0, 0};
        #pragma unroll
        for (int t = 0; t < 2; ++t)
            #pragma unroll
            for (int g = 0; g < 4; ++g) {
                const int f = 16 * t + q4 + g;
                const f32x4 w4 = *(const f32x4*)(gw2 + f * 4);
                pg += silu_f(ag[t][g]) * w4;
            }
        #pragma unroll
        for (int o = 0; o < 4; ++o) pg[o] = qreduce(pg[o]);
        const f32x4 l = pg + *(const f32x4*)gb2;
        const float mx = fmaxf(fmaxf(l[0], l[1]), fmaxf(l[2], l[3]));
        f32x4 ee;
        #pragma unroll
        for (int o = 0; o < 4; ++o) ee[o] = __expf(l[o] - mx);
        gwt = ee * __builtin_amdgcn_rcpf(ee[0] + ee[1] + ee[2] + ee[3]);
    }
    __syncthreads();   // e0 ew1h0 ready in WA

    // ================= 4 experts: 4 pipelined phases each =================
    f32x4 moe[4] = {{0,0,0,0},{0,0,0,0},{0,0,0,0},{0,0,0,0}};
    #pragma unroll 1
    for (int e = 0; e < 4; ++e) {
        const f16* ebase = wsp + IMG_E + e * 16384;
        f32x4 a2e[4];
        #pragma unroll
        for (int t = 0; t < 4; ++t)
            a2e[t] = *(const f32x4*)(eb2 + e * 64 + t * 16 + q4);
        f16x8 eaB[2];
        // --- A (WA: ew1 h0): stage ew2h0 -> WB ---
        stage4<8192>(ebase + 4096 * 2, WB_3, wv, lane);
        {
            f32x4 aa[4];
            #pragma unroll
            for (int t = 0; t < 4; ++t)
                aa[t] = *(const f32x4*)(eb1 + e * 128 + t * 16 + q4);
            mmN<4>(hbB, WA, aa, lane);
            silu_pack(aa, eaB);
        }
        __syncthreads();
        // --- B (WB: ew2 h0): stage ew1h1 -> WA ---
        stage4<8192>(ebase + 8192, WA_3, wv, lane);
        mmN<4>(eaB, WB, a2e, lane);
        __syncthreads();
        // --- C (WA: ew1 h1): stage ew2h1 -> WB ---
        stage4<8192>(ebase + 8192 + 4096, WB_3, wv, lane);
        {
            f32x4 aa[4];
            #pragma unroll
            for (int t = 0; t < 4; ++t)
                aa[t] = *(const f32x4*)(eb1 + e * 128 + 64 + t * 16 + q4);
            mmN<4>(hbB, WA, aa, lane);
            silu_pack(aa, eaB);
        }
        __syncthreads();
        // --- D (WB: ew2 h1): stage next ew1h0 (or sw) -> WA ---
        if (e < 3) stage4<8192>(wsp + IMG_E + (e + 1) * 16384, WA_3, wv, lane);
        else       stage4<8192>(wsp + IMG_SWH, WA_3, wv, lane);
        mmN<4>(eaB, WB, a2e, lane);
        const float ge = (e == 0) ? gwt[0] : (e == 1) ? gwt[1] : (e == 2) ? gwt[2] : gwt[3];
        #pragma unroll
        for (int t = 0; t < 4; ++t)
            #pragma unroll
            for (int g = 0; g < 4; ++g)
                moe[t][g] += silu_f(a2e[t][g]) * ge;
        __syncthreads();
    }

    // ================= feat (WA: sw): stage hw1[0,1] -> WB, hw1[2] -> G ============
    stage4<8192>(wsp + IMG_SWH + 4096, WB_3, wv, lane);
    stage4<4096>(wsp + IMG_SWH + 8192, G_3, wv, lane);
    f16x8 featB[2];
    {
        f16x8 moeB[2];
        pack_raw(moe, moeB);
        f32x4 fs[4];
        #pragma unroll
        for (int t = 0; t < 4; ++t)
            fs[t] = *(const f32x4*)(sb + t * 16 + q4);
        mmN<4>(moeB, WA, fs, lane);
        silu_pack(fs, featB);
    }
    __syncthreads();   // hw1[0,1] in WB, hw1[2] in G

    // ================= heads (WB: hw1[0]@0, hw1[1]@2048; G: hw1[2]) ================
    #pragma unroll
    for (int h = 0; h < 3; ++h) {
        const f16* hw = (h == 0) ? WB : (h == 1) ? (WB + 2048) : G;
        f32x4 ah[2];
        #pragma unroll
        for (int t = 0; t < 2; ++t)
            ah[t] = *(const f32x4*)(hb1 + h * 32 + t * 16 + q4);
        mmN<2>(featB, hw, ah, lane);
        float ph = 0.f;
        #pragma unroll
        for (int t = 0; t < 2; ++t) {
            const f32x4 w4 = *(const f32x4*)(hw2 + h * 32 + t * 16 + q4);
            #pragma unroll
            for (int g = 0; g < 4; ++g)
                ph += silu_f(ah[t][g]) * w4[g];
        }
        ph = qreduce(ph);
        if (q == h) out[(row0 + j) * 3 + h] = ph + hb2[h];
    }
}

extern "C" void kernel_launch(void* const* d_in, const int* in_sizes, int n_in,
                              void* d_out, int out_size, void* d_ws, size_t ws_size,
                              hipStream_t stream) {
    const float* x    = (const float*)d_in[0];
    const float* w1   = (const float*)d_in[1];
    const float* b1   = (const float*)d_in[2];
    const float* lng  = (const float*)d_in[3];
    const float* lnb  = (const float*)d_in[4];
    const float* w2   = (const float*)d_in[5];
    const float* b2   = (const float*)d_in[6];
    const float* ew1  = (const float*)d_in[7];
    const float* eb1  = (const float*)d_in[8];
    const float* ew2  = (const float*)d_in[9];
    const float* eb2  = (const float*)d_in[10];
    const float* gw1  = (const float*)d_in[11];
    const float* gb1  = (const float*)d_in[12];
    const float* gw2  = (const float*)d_in[13];
    const float* gb2  = (const float*)d_in[14];
    const float* sw   = (const float*)d_in[15];
    const float* sb   = (const float*)d_in[16];
    const float* hw1  = (const float*)d_in[17];
    const float* hb1  = (const float*)d_in[18];
    const float* hw2  = (const float*)d_in[19];
    const float* hb2  = (const float*)d_in[20];
    float* out = (float*)d_out;
    f16* ws = (f16*)d_ws;

    hipLaunchKernelGGL(prep_weights, dim3(64), dim3(256), 0, stream,
                       w1, w2, gw1, ew1, ew2, sw, hw1, ws);

    const int B = in_sizes[0] / 256;
    const int grid = B / 64;
    hipLaunchKernelGGL(fused_net_mfma, dim3(grid), dim3(256), 0, stream,
                       x, ws, b1, lng, lnb, b2, eb1, eb2, gb1, gw2, gb2,
                       sb, hb1, hw2, hb2, out);
}